// Round 5
// baseline (83.178 us; speedup 1.0000x reference)
//
#include <hip/hip_runtime.h>
#include <hip/hip_bf16.h>

typedef _Float16 half8 __attribute__((ext_vector_type(8)));
typedef float f32x16 __attribute__((ext_vector_type(16)));
typedef float f32x4v __attribute__((ext_vector_type(4)));   // clang-native for nontemporal builtins

constexpr int KC = 256;      // clusters
constexpr int DD = 64;       // feature dim
constexpr int NN = 262144;   // points
constexpr int GRID = 1024;
constexpr int ITERS = 2;     // 128 cols per block-iteration (4 waves x 32)

// out[k][n] = A[k] + (mu[k].x[n] - 0.5*x2[n]) * C[k]
// A[k] = alpha[k] - 32*logvar[k] - 0.5*m2[k]*C[k],  C[k] = exp(-logvar[k])

__global__ __launch_bounds__(256, 4)
void gmm_ll_kernel(const float* __restrict__ X,
                   const float* __restrict__ mu,
                   const float* __restrict__ logvar,
                   const float* __restrict__ alpha,
                   float* __restrict__ out)
{
    // mu in f16, XOR-swizzled chunks: row r (128 B = 8 chunks), chunk s at slot s^(r&7)
    __shared__ __align__(16) unsigned char smu[KC * 128];
    __shared__ float2 AC[KC];

    const int tid = threadIdx.x;

    // ---------- setup: thread t owns cluster t ----------
    {
        const float* mrow = mu + tid * DD;
        float m2 = 0.f;
        #pragma unroll
        for (int s = 0; s < 8; ++s) {
            float4 v0 = *(const float4*)(mrow + 8 * s);
            float4 v1 = *(const float4*)(mrow + 8 * s + 4);
            m2 += v0.x*v0.x + v0.y*v0.y + v0.z*v0.z + v0.w*v0.w
                + v1.x*v1.x + v1.y*v1.y + v1.z*v1.z + v1.w*v1.w;
            half8 hch = { (_Float16)v0.x, (_Float16)v0.y, (_Float16)v0.z, (_Float16)v0.w,
                          (_Float16)v1.x, (_Float16)v1.y, (_Float16)v1.z, (_Float16)v1.w };
            *(half8*)(smu + tid * 128 + ((s ^ (tid & 7)) * 16)) = hch;
        }
        float lv = logvar[tid];
        float Cv = __expf(-lv);
        AC[tid] = make_float2(alpha[tid] - 32.0f * lv - 0.5f * m2 * Cv, Cv);
    }
    __syncthreads();

    const int l = tid & 63;
    const int w = tid >> 6;   // wave 0..3
    const int q = l & 31;     // column within wave tile / mu row selector
    const int h = l >> 5;     // k-half selector

    for (int it = 0; it < ITERS; ++it) {
        const int colb = (blockIdx.x * ITERS + it) * 128 + w * 32;
        const int col  = colb + q;
        const float* xr = X + (size_t)col * DD;

        // B fragments: lane holds X[col][16*kk + 8*h .. +7] for kk=0..3
        // nontemporal: X is single-use, keep it out of L2 retention
        half8 bf[4];
        float p = 0.f;
        #pragma unroll
        for (int kk = 0; kk < 4; ++kk) {
            f32x4v v0 = __builtin_nontemporal_load((const f32x4v*)(xr + kk * 16 + h * 8));
            f32x4v v1 = __builtin_nontemporal_load((const f32x4v*)(xr + kk * 16 + h * 8 + 4));
            p += v0.x*v0.x + v0.y*v0.y + v0.z*v0.z + v0.w*v0.w
               + v1.x*v1.x + v1.y*v1.y + v1.z*v1.z + v1.w*v1.w;
            bf[kk] = { (_Float16)v0.x, (_Float16)v0.y, (_Float16)v0.z, (_Float16)v0.w,
                       (_Float16)v1.x, (_Float16)v1.y, (_Float16)v1.z, (_Float16)v1.w };
        }
        // full ||x||^2 in fp32: partner lane (l^32) holds the other k-half
        p += __shfl_xor(p, 32, 64);
        const float hx2 = 0.5f * p;

        #pragma unroll 2
        for (int c = 0; c < 8; ++c) {
            f32x16 acc = {0.f,0.f,0.f,0.f,0.f,0.f,0.f,0.f,
                          0.f,0.f,0.f,0.f,0.f,0.f,0.f,0.f};
            const int r = 32 * c + q;            // mu row this lane feeds
            const unsigned rbase = (unsigned)r * 128u;
            const unsigned sw = (unsigned)(q & 7);
            #pragma unroll
            for (int kk = 0; kk < 4; ++kk) {
                // A frag: row = lane&31, k = 8*(lane>>5)+e  -> chunk 2*kk + h
                half8 af = *(const half8*)(smu + rbase + ((((unsigned)(2*kk + h)) ^ sw) * 16));
                acc = __builtin_amdgcn_mfma_f32_32x32x16_f16(af, bf[kk], acc, 0, 0, 0);
            }
            // D layout: col = lane&31, row = (reg&3) + 8*(reg>>2) + 4*(lane>>5)
            // each store: full 128-B lines, nontemporal (out never re-read)
            #pragma unroll
            for (int g = 0; g < 4; ++g) {
                const int Rb = 32 * c + 8 * g + 4 * h;
                #pragma unroll
                for (int j = 0; j < 4; ++j) {
                    const float2 ac = AC[Rb + j];
                    __builtin_nontemporal_store(ac.x + (acc[4 * g + j] - hx2) * ac.y,
                                                &out[(size_t)(Rb + j) * NN + col]);
                }
            }
        }
    }
}

extern "C" void kernel_launch(void* const* d_in, const int* in_sizes, int n_in,
                              void* d_out, int out_size, void* d_ws, size_t ws_size,
                              hipStream_t stream)
{
    const float* X  = (const float*)d_in[0];
    const float* mu = (const float*)d_in[1];
    const float* lv = (const float*)d_in[2];
    const float* al = (const float*)d_in[3];
    float* out = (float*)d_out;
    gmm_ll_kernel<<<GRID, 256, 0, stream>>>(X, mu, lv, al, out);
}

// Round 6
// 79.429 us; speedup vs baseline: 1.0472x; 1.0472x over previous
//
#include <hip/hip_runtime.h>
#include <hip/hip_bf16.h>

typedef _Float16 half8 __attribute__((ext_vector_type(8)));
typedef float f32x16 __attribute__((ext_vector_type(16)));

constexpr int KC = 256;      // clusters
constexpr int DD = 64;       // feature dim
constexpr int NN = 262144;   // points
constexpr int GRID = 1024;   // x 256 cols/block = N

// out[k][n] = A[k] + (mu[k].x[n] - 0.5*x2[n]) * C[k]
// A[k] = alpha[k] - 32*logvar[k] - 0.5*m2[k]*C[k],  C[k] = exp(-logvar[k])

__global__ __launch_bounds__(512, 8)
void gmm_ll_kernel(const float* __restrict__ X,
                   const float* __restrict__ mu,
                   const float* __restrict__ logvar,
                   const float* __restrict__ alpha,
                   float* __restrict__ out)
{
    // mu in f16, XOR-swizzled chunks: row r (128 B = 8 chunks), chunk s at slot s^(r&7)
    __shared__ __align__(16) unsigned char smu[KC * 128];
    __shared__ float2 AC[KC];

    const int tid = threadIdx.x;

    // ---------- setup: threads 0..255 own one cluster each ----------
    if (tid < KC) {
        const float* mrow = mu + tid * DD;
        float m2 = 0.f;
        #pragma unroll
        for (int s = 0; s < 8; ++s) {
            float4 v0 = *(const float4*)(mrow + 8 * s);
            float4 v1 = *(const float4*)(mrow + 8 * s + 4);
            m2 += v0.x*v0.x + v0.y*v0.y + v0.z*v0.z + v0.w*v0.w
                + v1.x*v1.x + v1.y*v1.y + v1.z*v1.z + v1.w*v1.w;
            half8 hch = { (_Float16)v0.x, (_Float16)v0.y, (_Float16)v0.z, (_Float16)v0.w,
                          (_Float16)v1.x, (_Float16)v1.y, (_Float16)v1.z, (_Float16)v1.w };
            *(half8*)(smu + tid * 128 + ((s ^ (tid & 7)) * 16)) = hch;
        }
        float lv = logvar[tid];
        float Cv = __expf(-lv);
        AC[tid] = make_float2(alpha[tid] - 32.0f * lv - 0.5f * m2 * Cv, Cv);
    }
    __syncthreads();

    const int l = tid & 63;
    const int w = tid >> 6;   // wave 0..7
    const int q = l & 31;     // column within wave tile / mu row selector
    const int h = l >> 5;     // k-half selector

    const int col = blockIdx.x * 256 + w * 32 + q;
    const float* xr = X + (size_t)col * DD;

    // B fragments: lane holds X[col][16*kk + 8*h .. +7] for kk=0..3
    half8 bf[4];
    float p = 0.f;
    #pragma unroll
    for (int kk = 0; kk < 4; ++kk) {
        float4 v0 = *(const float4*)(xr + kk * 16 + h * 8);
        float4 v1 = *(const float4*)(xr + kk * 16 + h * 8 + 4);
        p += v0.x*v0.x + v0.y*v0.y + v0.z*v0.z + v0.w*v0.w
           + v1.x*v1.x + v1.y*v1.y + v1.z*v1.z + v1.w*v1.w;
        bf[kk] = { (_Float16)v0.x, (_Float16)v0.y, (_Float16)v0.z, (_Float16)v0.w,
                   (_Float16)v1.x, (_Float16)v1.y, (_Float16)v1.z, (_Float16)v1.w };
    }
    // full ||x||^2 in fp32: partner lane (l^32) holds the other k-half
    p += __shfl_xor(p, 32, 64);
    const float hx2 = 0.5f * p;

    #pragma unroll 2
    for (int c = 0; c < 8; ++c) {
        f32x16 acc = {0.f,0.f,0.f,0.f,0.f,0.f,0.f,0.f,
                      0.f,0.f,0.f,0.f,0.f,0.f,0.f,0.f};
        const int r = 32 * c + q;            // mu row this lane feeds
        const unsigned rbase = (unsigned)r * 128u;
        const unsigned sw = (unsigned)(q & 7);
        #pragma unroll
        for (int kk = 0; kk < 4; ++kk) {
            // A frag: row = lane&31, k = 8*(lane>>5)+e  -> chunk 2*kk + h
            half8 af = *(const half8*)(smu + rbase + ((((unsigned)(2*kk + h)) ^ sw) * 16));
            acc = __builtin_amdgcn_mfma_f32_32x32x16_f16(af, bf[kk], acc, 0, 0, 0);
        }
        // D layout: col = lane&31, row = (reg&3) + 8*(reg>>2) + 4*(lane>>5)
        // each store instruction covers two full 128-B lines
        #pragma unroll
        for (int g = 0; g < 4; ++g) {
            const int Rb = 32 * c + 8 * g + 4 * h;
            #pragma unroll
            for (int j = 0; j < 4; ++j) {
                const float2 ac = AC[Rb + j];
                out[(size_t)(Rb + j) * NN + col] = ac.x + (acc[4 * g + j] - hx2) * ac.y;
            }
        }
    }
}

extern "C" void kernel_launch(void* const* d_in, const int* in_sizes, int n_in,
                              void* d_out, int out_size, void* d_ws, size_t ws_size,
                              hipStream_t stream)
{
    const float* X  = (const float*)d_in[0];
    const float* mu = (const float*)d_in[1];
    const float* lv = (const float*)d_in[2];
    const float* al = (const float*)d_in[3];
    float* out = (float*)d_out;
    gmm_ll_kernel<<<GRID, 512, 0, stream>>>(X, mu, lv, al, out);
}

// Round 7
// 73.195 us; speedup vs baseline: 1.1364x; 1.0852x over previous
//
#include <hip/hip_runtime.h>
#include <hip/hip_bf16.h>

typedef _Float16 half8 __attribute__((ext_vector_type(8)));
typedef float f32x16 __attribute__((ext_vector_type(16)));

constexpr int KC = 256;      // clusters
constexpr int DD = 64;       // feature dim
constexpr int NN = 262144;   // points
constexpr int GRID = 256;    // blocks; each owns NCH*256 = 1024 cols
constexpr int NCH = 4;       // column chunks per block

// out[k][n] = A[k] + (mu[k].x[n] - 0.5*x2[n]) * C[k]
// A[k] = alpha[k] - 32*logvar[k] - 0.5*m2[k]*C[k],  C[k] = exp(-logvar[k])

__global__ __launch_bounds__(512, 2)
void gmm_ll_kernel(const float* __restrict__ X,
                   const float* __restrict__ mu,
                   const float* __restrict__ logvar,
                   const float* __restrict__ alpha,
                   float* __restrict__ out)
{
    // mu in f16, XOR-swizzled chunks: row r (128 B = 8 chunks), chunk s at slot s^(r&7)
    __shared__ __align__(16) unsigned char smu[KC * 128];
    __shared__ float2 AC[KC];

    const int tid = threadIdx.x;

    // ---------- setup: threads 0..255 own one cluster each ----------
    if (tid < KC) {
        const float* mrow = mu + tid * DD;
        float m2 = 0.f;
        #pragma unroll
        for (int s = 0; s < 8; ++s) {
            float4 v0 = *(const float4*)(mrow + 8 * s);
            float4 v1 = *(const float4*)(mrow + 8 * s + 4);
            m2 += v0.x*v0.x + v0.y*v0.y + v0.z*v0.z + v0.w*v0.w
                + v1.x*v1.x + v1.y*v1.y + v1.z*v1.z + v1.w*v1.w;
            half8 hch = { (_Float16)v0.x, (_Float16)v0.y, (_Float16)v0.z, (_Float16)v0.w,
                          (_Float16)v1.x, (_Float16)v1.y, (_Float16)v1.z, (_Float16)v1.w };
            *(half8*)(smu + tid * 128 + ((s ^ (tid & 7)) * 16)) = hch;
        }
        float lv = logvar[tid];
        float Cv = __expf(-lv);
        AC[tid] = make_float2(alpha[tid] - 32.0f * lv - 0.5f * m2 * Cv, Cv);
    }

    const int l = tid & 63;
    const int w = tid >> 6;   // wave 0..7
    const int q = l & 31;     // column within 32-col window / mu row selector
    const int h = l >> 5;     // k-half selector

    // XCD-aware bijective swizzle (GRID % 8 == 0): contiguous col range per XCD
    const int b  = blockIdx.x;
    const int bs = (b & 7) * (GRID / 8) + (b >> 3);
    const int col0 = bs * (NCH * 256) + w * 32 + q;

    // ---------- X fragments for all chunks, kept in registers ----------
    half8 bf[NCH][4];
    float hx2[NCH];
    #pragma unroll
    for (int ch = 0; ch < NCH; ++ch) {
        const float* xr = X + (size_t)(col0 + ch * 256) * DD;
        float p = 0.f;
        #pragma unroll
        for (int kk = 0; kk < 4; ++kk) {
            float4 v0 = *(const float4*)(xr + kk * 16 + h * 8);
            float4 v1 = *(const float4*)(xr + kk * 16 + h * 8 + 4);
            p += v0.x*v0.x + v0.y*v0.y + v0.z*v0.z + v0.w*v0.w
               + v1.x*v1.x + v1.y*v1.y + v1.z*v1.z + v1.w*v1.w;
            bf[ch][kk] = { (_Float16)v0.x, (_Float16)v0.y, (_Float16)v0.z, (_Float16)v0.w,
                           (_Float16)v1.x, (_Float16)v1.y, (_Float16)v1.z, (_Float16)v1.w };
        }
        p += __shfl_xor(p, 32, 64);   // partner lane holds the other k-half
        hx2[ch] = 0.5f * p;
    }
    __syncthreads();

    #pragma unroll 1
    for (int c = 0; c < 8; ++c) {
        const unsigned rbase = (unsigned)(32 * c + q) * 128u;
        const unsigned sw = (unsigned)(q & 7);
        half8 af[4];
        #pragma unroll
        for (int kk = 0; kk < 4; ++kk)
            af[kk] = *(const half8*)(smu + rbase + ((((unsigned)(2 * kk + h)) ^ sw) * 16));

        f32x16 acc[NCH];
        #pragma unroll
        for (int ch = 0; ch < NCH; ++ch) {
            acc[ch] = (f32x16){0.f,0.f,0.f,0.f,0.f,0.f,0.f,0.f,
                               0.f,0.f,0.f,0.f,0.f,0.f,0.f,0.f};
            #pragma unroll
            for (int kk = 0; kk < 4; ++kk)
                acc[ch] = __builtin_amdgcn_mfma_f32_32x32x16_f16(af[kk], bf[ch][kk], acc[ch], 0, 0, 0);
        }

        // D layout: col = lane&31, row = (reg&3) + 8*(reg>>2) + 4*(lane>>5)
        // store order (g, j, ch): per k-row, the block emits a tight 4-KB burst
        #pragma unroll
        for (int g = 0; g < 4; ++g) {
            const int Rb = 32 * c + 8 * g + 4 * h;
            #pragma unroll
            for (int j = 0; j < 4; ++j) {
                const float2 ac = AC[Rb + j];
                float* po = out + (size_t)(Rb + j) * NN + col0;
                #pragma unroll
                for (int ch = 0; ch < NCH; ++ch)
                    po[ch * 256] = ac.x + (acc[ch][4 * g + j] - hx2[ch]) * ac.y;
            }
        }
    }
}

extern "C" void kernel_launch(void* const* d_in, const int* in_sizes, int n_in,
                              void* d_out, int out_size, void* d_ws, size_t ws_size,
                              hipStream_t stream)
{
    const float* X  = (const float*)d_in[0];
    const float* mu = (const float*)d_in[1];
    const float* lv = (const float*)d_in[2];
    const float* al = (const float*)d_in[3];
    float* out = (float*)d_out;
    gmm_ll_kernel<<<GRID, 512, 0, stream>>>(X, mu, lv, al, out);
}

// Round 8
// 67.893 us; speedup vs baseline: 1.2251x; 1.0781x over previous
//
#include <hip/hip_runtime.h>
#include <hip/hip_bf16.h>

typedef _Float16 half8 __attribute__((ext_vector_type(8)));
typedef float f32x16 __attribute__((ext_vector_type(16)));

constexpr int KC = 256;      // clusters
constexpr int DD = 64;       // feature dim
constexpr int NN = 262144;   // points
constexpr int GRID = 256;    // blocks; each owns NCH*256 = 1024 cols
constexpr int NCH = 4;       // column chunks per block

// out[k][n] = A[k] + (mu[k].x[n] - 0.5*x2[n]) * C[k]
// A[k] = alpha[k] - 32*logvar[k] - 0.5*m2[k]*C[k],  C[k] = exp(-logvar[k])

__global__ __launch_bounds__(512, 2)
void gmm_ll_kernel(const float* __restrict__ X,
                   const float* __restrict__ mu,
                   const float* __restrict__ logvar,
                   const float* __restrict__ alpha,
                   float* __restrict__ out)
{
    // mu in f16, XOR-swizzled chunks: row r (128 B = 8 chunks), chunk s at slot s^(r&7)
    __shared__ __align__(16) unsigned char smu[KC * 128];
    __shared__ float2 AC[KC];

    const int tid = threadIdx.x;

    // ---------- setup: threads 0..255 own one cluster each ----------
    if (tid < KC) {
        const float* mrow = mu + tid * DD;
        float m2 = 0.f;
        #pragma unroll
        for (int s = 0; s < 8; ++s) {
            float4 v0 = *(const float4*)(mrow + 8 * s);
            float4 v1 = *(const float4*)(mrow + 8 * s + 4);
            m2 += v0.x*v0.x + v0.y*v0.y + v0.z*v0.z + v0.w*v0.w
                + v1.x*v1.x + v1.y*v1.y + v1.z*v1.z + v1.w*v1.w;
            half8 hch = { (_Float16)v0.x, (_Float16)v0.y, (_Float16)v0.z, (_Float16)v0.w,
                          (_Float16)v1.x, (_Float16)v1.y, (_Float16)v1.z, (_Float16)v1.w };
            *(half8*)(smu + tid * 128 + ((s ^ (tid & 7)) * 16)) = hch;
        }
        float lv = logvar[tid];
        float Cv = __expf(-lv);
        AC[tid] = make_float2(alpha[tid] - 32.0f * lv - 0.5f * m2 * Cv, Cv);
    }

    const int l = tid & 63;
    const int w = tid >> 6;   // wave 0..7
    const int q = l & 31;     // column within 32-col window / mu row selector
    const int h = l >> 5;     // k-half selector

    // XCD-aware bijective swizzle (GRID % 8 == 0): contiguous col range per XCD
    const int b  = blockIdx.x;
    const int bs = (b & 7) * (GRID / 8) + (b >> 3);
    const int col0 = bs * (NCH * 256) + w * 32 + q;

    // ---------- X fragments for all chunks, kept in registers ----------
    // (normal loads: each 128-B X line is touched by 4 instructions; nt-loads
    //  would defeat the cache merge of those touches — that was R5's regression)
    half8 bf[NCH][4];
    float hx2[NCH];
    #pragma unroll
    for (int ch = 0; ch < NCH; ++ch) {
        const float* xr = X + (size_t)(col0 + ch * 256) * DD;
        float p = 0.f;
        #pragma unroll
        for (int kk = 0; kk < 4; ++kk) {
            float4 v0 = *(const float4*)(xr + kk * 16 + h * 8);
            float4 v1 = *(const float4*)(xr + kk * 16 + h * 8 + 4);
            p += v0.x*v0.x + v0.y*v0.y + v0.z*v0.z + v0.w*v0.w
               + v1.x*v1.x + v1.y*v1.y + v1.z*v1.z + v1.w*v1.w;
            bf[ch][kk] = { (_Float16)v0.x, (_Float16)v0.y, (_Float16)v0.z, (_Float16)v0.w,
                           (_Float16)v1.x, (_Float16)v1.y, (_Float16)v1.z, (_Float16)v1.w };
        }
        p += __shfl_xor(p, 32, 64);   // partner lane holds the other k-half
        hx2[ch] = 0.5f * p;
    }
    __syncthreads();

    #pragma unroll 1
    for (int c = 0; c < 8; ++c) {
        const unsigned rbase = (unsigned)(32 * c + q) * 128u;
        const unsigned sw = (unsigned)(q & 7);
        half8 af[4];
        #pragma unroll
        for (int kk = 0; kk < 4; ++kk)
            af[kk] = *(const half8*)(smu + rbase + ((((unsigned)(2 * kk + h)) ^ sw) * 16));

        f32x16 acc[NCH];
        #pragma unroll
        for (int ch = 0; ch < NCH; ++ch) {
            acc[ch] = (f32x16){0.f,0.f,0.f,0.f,0.f,0.f,0.f,0.f,
                               0.f,0.f,0.f,0.f,0.f,0.f,0.f,0.f};
            #pragma unroll
            for (int kk = 0; kk < 4; ++kk)
                acc[ch] = __builtin_amdgcn_mfma_f32_32x32x16_f16(af[kk], bf[ch][kk], acc[ch], 0, 0, 0);
        }

        // D layout: col = lane&31, row = (reg&3) + 8*(reg>>2) + 4*(lane>>5)
        // full-line stores in (g, j, ch) order -> 4-KB burst per k-row per block;
        // nontemporal: stream past L2, preserve burst order, don't evict X
        #pragma unroll
        for (int g = 0; g < 4; ++g) {
            const int Rb = 32 * c + 8 * g + 4 * h;
            #pragma unroll
            for (int j = 0; j < 4; ++j) {
                const float2 ac = AC[Rb + j];
                float* po = out + (size_t)(Rb + j) * NN + col0;
                #pragma unroll
                for (int ch = 0; ch < NCH; ++ch)
                    __builtin_nontemporal_store(
                        ac.x + (acc[ch][4 * g + j] - hx2[ch]) * ac.y, &po[ch * 256]);
            }
        }
    }
}

extern "C" void kernel_launch(void* const* d_in, const int* in_sizes, int n_in,
                              void* d_out, int out_size, void* d_ws, size_t ws_size,
                              hipStream_t stream)
{
    const float* X  = (const float*)d_in[0];
    const float* mu = (const float*)d_in[1];
    const float* lv = (const float*)d_in[2];
    const float* al = (const float*)d_in[3];
    float* out = (float*)d_out;
    gmm_ll_kernel<<<GRID, 512, 0, stream>>>(X, mu, lv, al, out);
}